// Round 1
// baseline (823.483 us; speedup 1.0000x reference)
//
#include <hip/hip_runtime.h>
#include <hip/hip_bf16.h>

// Problem constants (shapes fixed by the reference)
#define SRCL 512
#define BSZ  16
#define SNTL 512
#define CDIM 512          // C == E == 512
#define KDIM 512
#define VOC  12000
#define EXTN 500
#define MROWS (SRCL*BSZ)  // 8192
#define TOTV (VOC+EXTN)   // 12500
#define NPAD 12032        // Wgen rows padded to 94*128 so GEMM2 has no bounds checks
#define LL_SIZE ((size_t)MROWS * TOTV)   // 102,400,000

typedef __attribute__((ext_vector_type(8))) short bf16x8;   // 8 bf16 (4 VGPRs)
typedef __attribute__((ext_vector_type(4))) float f32x4;

__device__ __forceinline__ unsigned short f2bf(float x) {
  union { __hip_bfloat16 b; unsigned short u; } c;
  c.b = __float2bfloat16(x);
  return c.u;
}
__device__ __forceinline__ float bflo(unsigned int u) { return __uint_as_float(u << 16); }
__device__ __forceinline__ float bfhi(unsigned int u) { return __uint_as_float(u & 0xffff0000u); }

__device__ __forceinline__ void gload16(const void* g, void* l) {
  // async global->LDS, 16B per lane; LDS dest is wave-uniform base + lane*16
  __builtin_amdgcn_global_load_lds(
      (const __attribute__((address_space(1))) unsigned int*)g,
      (__attribute__((address_space(3))) unsigned int*)l, 16, 0, 0);
}

__device__ __forceinline__ float wred_max(float v) {
  for (int o = 32; o; o >>= 1) v = fmaxf(v, __shfl_down(v, o, 64));
  return v;
}
__device__ __forceinline__ float wred_sum(float v) {
  for (int o = 32; o; o >>= 1) v += __shfl_down(v, o, 64);
  return v;
}

// ---------------------------------------------------------------------------
// fp32 -> bf16 conversion (vectorized float4 -> ushort4)
// ---------------------------------------------------------------------------
__global__ void cvt_kernel(const float* __restrict__ co, const float* __restrict__ wt,
                           const float* __restrict__ wg,
                           unsigned short* __restrict__ cob,
                           unsigned short* __restrict__ wtb,
                           unsigned short* __restrict__ wgb) {
  const int stride = gridDim.x * blockDim.x;
  const int t0 = blockIdx.x * blockDim.x + threadIdx.x;
  for (int i = t0; i < MROWS*KDIM/4; i += stride) {
    const float4 v = ((const float4*)co)[i];
    ushort4 o; o.x = f2bf(v.x); o.y = f2bf(v.y); o.z = f2bf(v.z); o.w = f2bf(v.w);
    ((ushort4*)cob)[i] = o;
  }
  for (int i = t0; i < CDIM*KDIM/4; i += stride) {
    const float4 v = ((const float4*)wt)[i];
    ushort4 o; o.x = f2bf(v.x); o.y = f2bf(v.y); o.z = f2bf(v.z); o.w = f2bf(v.w);
    ((ushort4*)wtb)[i] = o;
  }
  for (int i = t0; i < NPAD*KDIM/4; i += stride) {
    float4 v = make_float4(0.f, 0.f, 0.f, 0.f);
    if (i < VOC*KDIM/4) v = ((const float4*)wg)[i];
    ushort4 o; o.x = f2bf(v.x); o.y = f2bf(v.y); o.z = f2bf(v.z); o.w = f2bf(v.w);
    ((ushort4*)wgb)[i] = o;
  }
}

// ---------------------------------------------------------------------------
// bf16 MFMA GEMM, C = A(MxK) * B(NxK)^T, m97 structure upgraded:
//   128x128 tile, BK=64 (half the vmcnt(0)+barrier drains vs BK=32),
//   global_load_lds w=16 with inverse-swizzled GLOBAL source (rule #21:
//   linear LDS dest + pre-swizzled source + swizzled ds_read) so the 128B
//   row stride stays bank-conflict-free, T1 bijective XCD blockIdx swizzle.
// EPI=0: h = tanh(acc + bias[col]) -> bf16, ld=CDIM
// EPI=1: logits = acc + bias[col<VOC] -> fp32 at row*TOTV+col (into d_out)
// EPI=2: logits = acc + bias[col<VOC] -> bf16 at row*NPAD+col (into ws)
// ---------------------------------------------------------------------------
template<int EPI>
__launch_bounds__(256)
__global__ void gemm_bt(const short* __restrict__ A, const short* __restrict__ Bm,
                        const float* __restrict__ bias, void* __restrict__ outp) {
  __shared__ short As[128*64];   // one BK=64 K-tile, row-major [128][64]
  __shared__ short Bs[128*64];
  const int tid  = threadIdx.x;
  const int wave = tid >> 6;
  const int lane = tid & 63;

  // T1: XCD-chunked bijective swizzle (valid: nwg % 8 == 0 for both dispatches)
  const int nwg = gridDim.x * gridDim.y;
  int bid = blockIdx.y * gridDim.x + blockIdx.x;
  bid = (bid & 7) * (nwg >> 3) + (bid >> 3);
  const int bx = bid % gridDim.x;
  const int by = bid / gridDim.x;
  const int m0 = by * 128;
  const int n0 = bx * 128;

  // staging: wave w stages rows [32w,32w+32) of each 128x64 tile in 4 loads
  // of 8 rows; lane -> (row = lane>>3, chunk = lane&7 of 8 bf16).
  // swizzle: LDS chunk q of row r holds global chunk q ^ (r&7); here r&7 ==
  // lane>>3, so the pre-swizzled source k-offset is ((lane&7)^(lane>>3))*8.
  const int srow = lane >> 3;
  const int ssk  = ((lane & 7) ^ srow) * 8;
  const size_t aBase = (size_t)(m0 + wave*32 + srow) * KDIM + ssk;
  const size_t bBase = (size_t)(n0 + wave*32 + srow) * KDIM + ssk;
  short* lA = As + wave*32*64;
  short* lB = Bs + wave*32*64;

  // compute: wave (wm,wn) owns a 64x64 quadrant = 4x4 subtiles of 16x16
  const int wm = wave & 1, wn = wave >> 1;
  const int quad = lane >> 4, r16 = lane & 15;
  const int rsw  = r16 & 7;                 // read-side swizzle key (row&7)
  const int aoffb = (wm*64 + r16) * 64;     // short offset of A-frag row
  const int boffb = (wn*64 + r16) * 64;

  f32x4 acc[4][4];
#pragma unroll
  for (int i = 0; i < 4; ++i)
#pragma unroll
    for (int j = 0; j < 4; ++j) acc[i][j] = (f32x4){0.f,0.f,0.f,0.f};

  for (int kt = 0; kt < KDIM/64; ++kt) {
    const size_t ko = (size_t)kt * 64;
    __syncthreads();                       // prev iter's LDS reads done
#pragma unroll
    for (int j = 0; j < 4; ++j) {
      gload16(A  + aBase + ko + (size_t)j*8*KDIM, lA + j*512);
      gload16(Bm + bBase + ko + (size_t)j*8*KDIM, lB + j*512);
    }
    __syncthreads();                       // staging visible (vmcnt(0) drain)
#pragma unroll
    for (int ks = 0; ks < 2; ++ks) {
      const int kc = ((ks*4 + quad) ^ rsw) * 8;   // swizzled 16B chunk offset
      bf16x8 af[4], bf[4];
#pragma unroll
      for (int i = 0; i < 4; ++i) {
        af[i] = *(const bf16x8*)(As + aoffb + i*1024 + kc);  // ds_read_b128
        bf[i] = *(const bf16x8*)(Bs + boffb + i*1024 + kc);
      }
#pragma unroll
      for (int mi = 0; mi < 4; ++mi)
#pragma unroll
        for (int ni = 0; ni < 4; ++ni)
          acc[mi][ni] = __builtin_amdgcn_mfma_f32_16x16x32_bf16(af[mi], bf[ni], acc[mi][ni], 0, 0, 0);
    }
  }

  // epilogue; C/D layout: col = lane&15, row = quad*4 + reg  (m89-verified)
#pragma unroll
  for (int mi = 0; mi < 4; ++mi) {
#pragma unroll
    for (int ni = 0; ni < 4; ++ni) {
#pragma unroll
      for (int r = 0; r < 4; ++r) {
        const int row = m0 + wm*64 + mi*16 + quad*4 + r;
        const int col = n0 + wn*64 + ni*16 + r16;
        float v = acc[mi][ni][r];
        if constexpr (EPI == 0) {
          v = tanhf(v + bias[col]);
          ((unsigned short*)outp)[(size_t)row * CDIM + col] = f2bf(v);
        } else if constexpr (EPI == 1) {
          v += (col < VOC) ? bias[col] : 0.f;
          ((float*)outp)[(size_t)row * TOTV + col] = v;   // pad cols overwritten later
        } else {
          v += (col < VOC) ? bias[col] : 0.f;
          ((unsigned short*)outp)[(size_t)row * NPAD + col] = f2bf(v);  // pad cols never read
        }
      }
    }
  }
}

// ---------------------------------------------------------------------------
// per-row: gates = softmax3(h.Wd + bd) (fused, was its own kernel),
// softmax(logits)*gen_gate, scatter-add copy probs, log -> ll
// one block (1024 thr = 16 waves) per row; ~50 KB LDS -> 2 blocks/CU
// BF16L=1: logits are bf16 ld=NPAD (in ws); BF16L=0: fp32 ld=TOTV (in d_out)
// ---------------------------------------------------------------------------
template<int BF16L>
__launch_bounds__(1024)
__global__ void finalize_kernel(const void* __restrict__ lg, float* __restrict__ out,
                                const __hip_bfloat16* __restrict__ hmat,
                                const float* __restrict__ Wd, const float* __restrict__ bd,
                                const int* __restrict__ copy_seq,
                                const float* __restrict__ align) {
  __shared__ __align__(16) float p[TOTV];
  __shared__ float scr[16];
  __shared__ float gscr[24];
  __shared__ float gv[3];
  const int m = blockIdx.x;      // = s*16 + b
  const int b = m & 15;
  const int tid = threadIdx.x;
  float* row = out + (size_t)m * TOTV;

  // gates: d_j = sum_c h[m,c]*Wd[j,c]; threads 0..511 each take one c
  {
    float d0 = 0.f, d1 = 0.f, d2 = 0.f;
    if (tid < CDIM) {
      const float hv = __bfloat162float(hmat[(size_t)m*CDIM + tid]);
      d0 = hv * Wd[tid];
      d1 = hv * Wd[CDIM + tid];
      d2 = hv * Wd[2*CDIM + tid];
    }
    d0 = wred_sum(d0); d1 = wred_sum(d1); d2 = wred_sum(d2);
    const int w = tid >> 6;
    if ((tid & 63) == 0 && w < 8) { gscr[w*3] = d0; gscr[w*3+1] = d1; gscr[w*3+2] = d2; }
  }
  __syncthreads();
  if (tid == 0) {
    float g0 = bd[0], g1 = bd[1], g2 = bd[2];
    for (int i = 0; i < 8; ++i) { g0 += gscr[i*3]; g1 += gscr[i*3+1]; g2 += gscr[i*3+2]; }
    const float mg = fmaxf(g0, fmaxf(g1, g2));
    const float e0 = __expf(g0-mg), e1 = __expf(g1-mg), e2 = __expf(g2-mg);
    const float inv3 = 1.f / (e0 + e1 + e2);
    gv[0] = e0*inv3; gv[1] = e1*inv3; gv[2] = e2*inv3;   // read after later barriers
  }

  // load logits into LDS (float4 ds_writes, conflict-free), tracking max
  float mx = -1e30f;
  if constexpr (BF16L) {
    const uint4* rowv = (const uint4*)((const unsigned short*)lg + (size_t)m * NPAD);
    for (int i = tid; i < VOC/8; i += 1024) {
      const uint4 q = rowv[i];
      float4 lo, hi;
      lo.x = bflo(q.x); lo.y = bfhi(q.x); lo.z = bflo(q.y); lo.w = bfhi(q.y);
      hi.x = bflo(q.z); hi.y = bfhi(q.z); hi.z = bflo(q.w); hi.w = bfhi(q.w);
      ((float4*)p)[i*2]   = lo;
      ((float4*)p)[i*2+1] = hi;
      mx = fmaxf(mx, fmaxf(fmaxf(fmaxf(lo.x,lo.y),fmaxf(lo.z,lo.w)),
                           fmaxf(fmaxf(hi.x,hi.y),fmaxf(hi.z,hi.w))));
    }
  } else {
    const float4* rowv = (const float4*)row;
    for (int i = tid; i < VOC/4; i += 1024) {
      const float4 v = rowv[i];
      ((float4*)p)[i] = v;
      mx = fmaxf(mx, fmaxf(fmaxf(v.x, v.y), fmaxf(v.z, v.w)));
    }
  }
  for (int i = VOC + tid; i < TOTV; i += 1024) p[i] = 0.f;

  mx = wred_max(mx);
  if ((tid & 63) == 0) scr[tid >> 6] = mx;
  __syncthreads();
  mx = scr[0];
#pragma unroll
  for (int i = 1; i < 16; ++i) mx = fmaxf(mx, scr[i]);
  __syncthreads();   // scr reuse

  float sm = 0.f;
  for (int i = tid; i < VOC; i += 1024) {
    const float e = __expf(p[i] - mx);
    p[i] = e;
    sm += e;
  }
  sm = wred_sum(sm);
  if ((tid & 63) == 0) scr[tid >> 6] = sm;
  __syncthreads();
  sm = scr[0];
#pragma unroll
  for (int i = 1; i < 16; ++i) sm += scr[i];

  const float gen  = gv[0];
  const float mapg = gv[1];
  const float cpg  = gv[2];
  const float scale = gen / sm;      // out_i = log(scale*(e_i + s_i/scale) + eps), exact algebra
  const float inv   = sm / gen;
  const float cw = cpg * inv, mw = mapg * inv;

  // scatter-add (1024 threads cover SNT=512 in one shot)
  if (tid < SNTL) {
    const float aw = align[(size_t)m * SNTL + tid];
    const int2 cs = *(const int2*)&copy_seq[(tid*BSZ + b)*2];
    atomicAdd(&p[cs.x], cw * aw);
    atomicAdd(&p[cs.y], mw * aw);
  }
  __syncthreads();

  for (int i = tid; i < TOTV/4; i += 1024) {
    const float4 v = ((const float4*)p)[i];
    float4 r;
    r.x = __logf(fmaf(v.x, scale, 1e-12f));
    r.y = __logf(fmaf(v.y, scale, 1e-12f));
    r.z = __logf(fmaf(v.z, scale, 1e-12f));
    r.w = __logf(fmaf(v.w, scale, 1e-12f));
    ((float4*)row)[i] = r;
  }
}

// ---------------------------------------------------------------------------
// arc_ll = log(arc_weight + 1e-12), float4-vectorized
// ---------------------------------------------------------------------------
__global__ void arc_kernel(const float4* __restrict__ arc, float4* __restrict__ out) {
  const int i = blockIdx.x * blockDim.x + threadIdx.x;
  if (i < (SRCL*BSZ*SRCL)/4) {
    const float4 v = arc[i];
    float4 r;
    r.x = __logf(v.x + 1e-12f);
    r.y = __logf(v.y + 1e-12f);
    r.z = __logf(v.z + 1e-12f);
    r.w = __logf(v.w + 1e-12f);
    out[i] = r;
  }
}

extern "C" void kernel_launch(void* const* d_in, const int* in_sizes, int n_in,
                              void* d_out, int out_size, void* d_ws, size_t ws_size,
                              hipStream_t stream) {
  (void)in_sizes; (void)n_in; (void)out_size;
  const float* align   = (const float*)d_in[0];
  const float* arc     = (const float*)d_in[1];
  const float* concept = (const float*)d_in[3];
  const int*   cseq    = (const int*)d_in[4];
  const float* Wt = (const float*)d_in[9];
  const float* bt = (const float*)d_in[10];
  const float* Wg = (const float*)d_in[11];
  const float* bg = (const float*)d_in[12];
  const float* Wd = (const float*)d_in[13];
  const float* bd = (const float*)d_in[14];
  float* out = (float*)d_out;

  // workspace layout
  unsigned short* cob = (unsigned short*)d_ws;          // 8192x512 bf16
  unsigned short* wtb = cob + (size_t)MROWS*KDIM;       // 512x512
  unsigned short* wgb = wtb + (size_t)CDIM*KDIM;        // 12032x512 (padded)
  unsigned short* hb  = wgb + (size_t)NPAD*KDIM;        // 8192x512
  unsigned short* logitsb = hb + (size_t)MROWS*KDIM;    // 8192x12032 bf16
  const size_t need = (size_t)((char*)(logitsb + (size_t)MROWS*NPAD) - (char*)d_ws);
  const bool use_bf16_logits = (ws_size >= need);   // ws_size constant per session

  cvt_kernel<<<2048, 256, 0, stream>>>(concept, Wt, Wg, cob, wtb, wgb);
  gemm_bt<0><<<dim3(CDIM/128, MROWS/128), 256, 0, stream>>>(
      (const short*)cob, (const short*)wtb, bt, (void*)hb);
  if (use_bf16_logits) {
    gemm_bt<2><<<dim3(NPAD/128, MROWS/128), 256, 0, stream>>>(
        (const short*)hb, (const short*)wgb, bg, (void*)logitsb);
    finalize_kernel<1><<<MROWS, 1024, 0, stream>>>(
        logitsb, out, (const __hip_bfloat16*)hb, Wd, bd, cseq, align);
  } else {
    gemm_bt<1><<<dim3(NPAD/128, MROWS/128), 256, 0, stream>>>(
        (const short*)hb, (const short*)wgb, bg, (void*)out);
    finalize_kernel<0><<<MROWS, 1024, 0, stream>>>(
        out, out, (const __hip_bfloat16*)hb, Wd, bd, cseq, align);
  }
  arc_kernel<<<4096, 256, 0, stream>>>((const float4*)arc, (float4*)(out + LL_SIZE));
}